// Round 1
// baseline (208.217 us; speedup 1.0000x reference)
//
#include <hip/hip_runtime.h>

// Problem constants (from reference setup_inputs)
#define BB   64          // batch
#define SS   512         // seq len
#define HH   768         // hidden dim
#define WW   256         // MAX_WORD_LEN (words per batch)
#define WE   300         // word-embedding dim
#define OUTD (HH + WE)   // 1068 output feature dim

// One block per (b, w). Waves 0-2 (192 threads) compute the segment-mean of
// hidden over the contiguous token run token_ids[b,:]==w (token_ids sorted
// per row => binary search gives [lo,hi)). Wave 3 (64 threads) copies the
// 300-float w2v row for word_ids[b,w]. All loads/stores are float4-aligned:
// hidden row stride 768 floats, w2v row stride 300 floats (1200 B, 16B
// aligned), out row stride 1068 floats (4272 B, 16B aligned).
__global__ __launch_bounds__(256)
void EmbeddingsModule_45311904973549_kernel(
    const float* __restrict__ hidden,     // [B, S, H]
    const float* __restrict__ w2v,        // [VOCAB, WE]
    const int*   __restrict__ token_ids,  // [B, S] sorted per row, in [0,W)
    const int*   __restrict__ word_ids,   // [B, W] in [0,VOCAB)
    float*       __restrict__ out)        // [B, W, OUTD]
{
    const int bw  = blockIdx.x;       // 0 .. B*W-1
    const int b   = bw >> 8;          // / WW
    const int w   = bw & (WW - 1);    // % WW
    const int tid = threadIdx.x;

    float* orow = out + (size_t)bw * OUTD;

    if (tid < 192) {
        // --- segment bounds via binary search (wave-uniform, cached) ---
        const int* tk = token_ids + b * SS;
        int lo, hi;
        {   // lower bound: first s with tk[s] >= w
            int l = 0, r = SS;
            while (l < r) { int m = (l + r) >> 1; if (tk[m] < w) l = m + 1; else r = m; }
            lo = l;
        }
        {   // upper bound: first s with tk[s] > w
            int l = lo, r = SS;
            while (l < r) { int m = (l + r) >> 1; if (tk[m] <= w) l = m + 1; else r = m; }
            hi = l;
        }
        const int   cnt = hi - lo;
        const float inv = (cnt > 0) ? (1.0f / (float)cnt) : 0.0f;

        // --- mean of hidden[b, lo:hi, tid*4 : tid*4+4] ---
        const float4* hrow = (const float4*)(hidden + (size_t)b * SS * HH);
        float4 acc = make_float4(0.f, 0.f, 0.f, 0.f);
        for (int s = lo; s < hi; ++s) {
            float4 v = hrow[(size_t)s * (HH / 4) + tid];
            acc.x += v.x; acc.y += v.y; acc.z += v.z; acc.w += v.w;
        }
        acc.x *= inv; acc.y *= inv; acc.z *= inv; acc.w *= inv;
        ((float4*)orow)[tid] = acc;     // out[b,w, 0:768]
    } else {
        // --- w2v gather: 75 float4s with 64 threads (j and j+64) ---
        const int     wid  = word_ids[bw];
        const float4* wrow = (const float4*)(w2v + (size_t)wid * WE);
        float4*       grow = (float4*)(orow + HH);   // out[b,w, 768:1068]
        for (int j = tid - 192; j < WE / 4; j += 64) {
            grow[j] = wrow[j];
        }
    }
}

extern "C" void kernel_launch(void* const* d_in, const int* in_sizes, int n_in,
                              void* d_out, int out_size, void* d_ws, size_t ws_size,
                              hipStream_t stream) {
    const float* hidden    = (const float*)d_in[0];
    const float* w2v       = (const float*)d_in[1];
    const int*   token_ids = (const int*)d_in[2];
    const int*   word_ids  = (const int*)d_in[3];
    float*       out       = (float*)d_out;

    EmbeddingsModule_45311904973549_kernel<<<BB * WW, 256, 0, stream>>>(
        hidden, w2v, token_ids, word_ids, out);
}